// Round 1
// baseline (316.296 us; speedup 1.0000x reference)
//
#include <hip/hip_runtime.h>

#define N_NODES 2048
#define C_CH    128
#define N_SPEC  10

// ---------------------------------------------------------------------------
// Kernel 1: bucket nodes by species. Single block; LDS atomics for positions.
// ---------------------------------------------------------------------------
__global__ __launch_bounds__(1024) void bucket_kernel(const int* __restrict__ index,
                                                      int* __restrict__ counts,
                                                      int* __restrict__ lists) {
    __shared__ int sc[N_SPEC];
    const int tid = threadIdx.x;
    if (tid < N_SPEC) sc[tid] = 0;
    __syncthreads();
    for (int n = tid; n < N_NODES; n += blockDim.x) {
        int s = index[n];
        int pos = atomicAdd(&sc[s], 1);
        lists[s * N_NODES + pos] = n;
    }
    __syncthreads();
    if (tid < N_SPEC) counts[tid] = sc[tid];
}

// ---------------------------------------------------------------------------
// Coefficient build: C[abj, i] = sum_k U[abj, k, il] * W[s, k, c]
// i = IOFF + il; i<8 goes to the float4-packed main plane, i==8 to scalar plane.
// ---------------------------------------------------------------------------
struct Params {
    const float* U3[3]; const float* W3[3];
    const float* U2[3]; const float* W2[3];
    const float* U1[3]; const float* W1[3];
};

template <int NAB, int MUL, int IRD, int IOFF>
__device__ inline void buildC(const float* __restrict__ u, const float* __restrict__ w,
                              int s, int c, float* __restrict__ sMain, float* __restrict__ sB) {
    const int tid = threadIdx.x;
    const float* wp = w + (s * MUL) * C_CH + c;
    for (int e = tid; e < NAB * IRD; e += 128) {
        int abj = e / IRD;
        int il  = e - abj * IRD;
        const float* up = u + (abj * MUL) * IRD + il;
        float acc = 0.f;
#pragma unroll
        for (int k = 0; k < MUL; ++k)
            acc += up[k * IRD] * wp[k * C_CH];
        int i = IOFF + il;
        if (i < 8) sMain[abj * 8 + i] = acc;
        else       sB[abj] = acc;
    }
}

// dynamic index into a register array without scratch: cndmask chain (a is 1..8)
__device__ inline float selx(const float x[9], int a) {
    float r = x[0];
    r = (a == 1) ? x[1] : r;
    r = (a == 2) ? x[2] : r;
    r = (a == 3) ? x[3] : r;
    r = (a == 4) ? x[4] : r;
    r = (a == 5) ? x[5] : r;
    r = (a == 6) ? x[6] : r;
    r = (a == 7) ? x[7] : r;
    r = (a == 8) ? x[8] : r;
    return r;
}

// ---------------------------------------------------------------------------
// Kernel 2: one block per (species, channel). Build C into LDS, then evaluate
// the cubic polynomial for 2 nodes per thread (256 node slots per pass).
// ---------------------------------------------------------------------------
__global__ __launch_bounds__(128) void sc_kernel(const float* __restrict__ nf,
                                                 const int* __restrict__ counts,
                                                 const int* __restrict__ lists,
                                                 Params p,
                                                 float* __restrict__ out) {
    __shared__ __align__(16) float sC3[729 * 8];  // [abj][i 0..7]
    __shared__ float sC3b[729];                   // [abj] i==8
    __shared__ __align__(16) float sC2[81 * 8];
    __shared__ float sC2b[81];
    __shared__ __align__(16) float sC1[9 * 8];
    __shared__ float sC1b[9];
    // total LDS = 29,484 B -> 5 blocks/CU; grid 1280 = exactly 5 blocks/CU

    const int s = blockIdx.x % N_SPEC;
    const int c = blockIdx.x / N_SPEC;
    const int tid = threadIdx.x;

    buildC<729, 10, 1, 0>(p.U3[0], p.W3[0], s, c, sC3, sC3b);
    buildC<729, 11, 3, 1>(p.U3[1], p.W3[1], s, c, sC3, sC3b);
    buildC<729, 13, 5, 4>(p.U3[2], p.W3[2], s, c, sC3, sC3b);
    buildC<81, 3, 1, 0>(p.U2[0], p.W2[0], s, c, sC2, sC2b);
    buildC<81, 2, 3, 1>(p.U2[1], p.W2[1], s, c, sC2, sC2b);
    buildC<81, 3, 5, 4>(p.U2[2], p.W2[2], s, c, sC2, sC2b);
    buildC<9, 1, 1, 0>(p.U1[0], p.W1[0], s, c, sC1, sC1b);
    buildC<9, 1, 3, 1>(p.U1[1], p.W1[1], s, c, sC1, sC1b);
    buildC<9, 1, 5, 4>(p.U1[2], p.W1[2], s, c, sC1, sC1b);
    __syncthreads();

    const int cnt = counts[s];
    const float4* C3v = (const float4*)sC3;
    const float4* C2v = (const float4*)sC2;
    const float4* C1v = (const float4*)sC1;

    for (int base = 0; base < cnt; base += 256) {
        const int i0 = base + tid;
        const int i1 = base + 128 + tid;
        const int m0 = (i0 < cnt) ? lists[s * N_NODES + i0] : -1;
        const int m1 = (i1 < cnt) ? lists[s * N_NODES + i1] : -1;

        // load x rows (clamped pointer for inactive slots; values unused)
        const float* x0p = nf + ((long)(m0 < 0 ? 0 : m0) * C_CH + c) * 9;
        const float* x1p = nf + ((long)(m1 < 0 ? 0 : m1) * C_CH + c) * 9;
        float x0[9], x1[9];
#pragma unroll
        for (int j = 0; j < 9; ++j) { x0[j] = x0p[j]; x1[j] = x1p[j]; }

        float4 o0a = {0, 0, 0, 0}, o0b = {0, 0, 0, 0};
        float4 o1a = {0, 0, 0, 0}, o1b = {0, 0, 0, 0};
        float o08 = 0.f, o18 = 0.f;

#pragma unroll 1  // keep a-loop rolled: body ~8KB stays I$-resident
        for (int a = 0; a < 9; ++a) {
            const float xa0 = selx(x0, a);
            const float xa1 = selx(x1, a);
            const float4 c1a = C1v[a * 2], c1b = C1v[a * 2 + 1];
            const float  c18 = sC1b[a];
            float4 q0a = c1a, q0b = c1b; float q08 = c18;
            float4 q1a = c1a, q1b = c1b; float q18 = c18;
#pragma unroll
            for (int b = 0; b < 9; ++b) {
                const int ab = a * 9 + b;
                const float4 c2a = C2v[ab * 2], c2b = C2v[ab * 2 + 1];
                const float  c28 = sC2b[ab];
                float4 t0a = c2a, t0b = c2b; float t08 = c28;
                float4 t1a = c2a, t1b = c2b; float t18 = c28;
#pragma unroll
                for (int j = 0; j < 9; ++j) {
                    const int abj = ab * 9 + j;
                    const float4 ca = C3v[abj * 2];
                    const float4 cb = C3v[abj * 2 + 1];
                    const float  c8 = sC3b[abj];
                    t0a += ca * x0[j]; t0b += cb * x0[j]; t08 += c8 * x0[j];
                    t1a += ca * x1[j]; t1b += cb * x1[j]; t18 += c8 * x1[j];
                }
                q0a += t0a * x0[b]; q0b += t0b * x0[b]; q08 += t08 * x0[b];
                q1a += t1a * x1[b]; q1b += t1b * x1[b]; q18 += t18 * x1[b];
            }
            o0a += q0a * xa0; o0b += q0b * xa0; o08 += q08 * xa0;
            o1a += q1a * xa1; o1b += q1b * xa1; o18 += q18 * xa1;
        }

        if (m0 >= 0) {
            float* op = out + ((long)m0 * C_CH + c) * 9;
            op[0] = o0a.x; op[1] = o0a.y; op[2] = o0a.z; op[3] = o0a.w;
            op[4] = o0b.x; op[5] = o0b.y; op[6] = o0b.z; op[7] = o0b.w;
            op[8] = o08;
        }
        if (m1 >= 0) {
            float* op = out + ((long)m1 * C_CH + c) * 9;
            op[0] = o1a.x; op[1] = o1a.y; op[2] = o1a.z; op[3] = o1a.w;
            op[4] = o1b.x; op[5] = o1b.y; op[6] = o1b.z; op[7] = o1b.w;
            op[8] = o18;
        }
    }
}

// ---------------------------------------------------------------------------
extern "C" void kernel_launch(void* const* d_in, const int* in_sizes, int n_in,
                              void* d_out, int out_size, void* d_ws, size_t ws_size,
                              hipStream_t stream) {
    const float* nf   = (const float*)d_in[0];
    const int* index  = (const int*)d_in[1];

    Params p;
    p.U3[0] = (const float*)d_in[2];  p.W3[0] = (const float*)d_in[3];
    p.U3[1] = (const float*)d_in[4];  p.W3[1] = (const float*)d_in[5];
    p.U3[2] = (const float*)d_in[6];  p.W3[2] = (const float*)d_in[7];
    p.U2[0] = (const float*)d_in[8];  p.W2[0] = (const float*)d_in[9];
    p.U2[1] = (const float*)d_in[10]; p.W2[1] = (const float*)d_in[11];
    p.U2[2] = (const float*)d_in[12]; p.W2[2] = (const float*)d_in[13];
    p.U1[0] = (const float*)d_in[14]; p.W1[0] = (const float*)d_in[15];
    p.U1[1] = (const float*)d_in[16]; p.W1[1] = (const float*)d_in[17];
    p.U1[2] = (const float*)d_in[18]; p.W1[2] = (const float*)d_in[19];

    int* counts = (int*)d_ws;        // 10 ints (aligned region start)
    int* lists  = (int*)d_ws + 16;   // 10 * 2048 ints

    bucket_kernel<<<1, 1024, 0, stream>>>(index, counts, lists);
    sc_kernel<<<N_SPEC * C_CH, 128, 0, stream>>>(nf, counts, lists, p, (float*)d_out);
}